// Round 1
// 572.843 us; speedup vs baseline: 21.6307x; 21.6307x over previous
//
#include <hip/hip_runtime.h>
#include <math.h>

#define N_ 2
#define A_ 5
#define C_ 12
#define H_ 256
#define G_ 512
// out = 4 * ifft_ortho(K * fft_ortho(...)) ==> 4/(512*512) on unnormalized FFTs
#define SCALE_ (4.0f / 262144.0f)
#define OUTF_ 655360       // out = fp32 REAL part, [2,5,256,256] (proven R6-R10)
#define HALFF_ 327680      // per-n float count
#define IMGC_ 131072       // 512*256 complex: one spectral half-plane (h2 elems)

// ---- fp16-pair scratch ------------------------------------------------------
struct __attribute__((aligned(4))) h2 { _Float16 x, y; };
__device__ __forceinline__ float2 ld2(const h2* p, size_t i) {
    h2 v = p[i]; return make_float2((float)v.x, (float)v.y);
}
__device__ __forceinline__ void st2(h2* p, size_t i, float2 v) {
    float x = fminf(fmaxf(v.x, -60000.f), 60000.f);   // never store inf
    float y = fminf(fmaxf(v.y, -60000.f), 60000.f);
    h2 o; o.x = (_Float16)x; o.y = (_Float16)y; p[i] = o;
}

__device__ __forceinline__ float2 cmul(float2 a, float2 b) {
    return make_float2(a.x * b.x - a.y * b.y, a.x * b.y + a.y * b.x);
}

__device__ __forceinline__ void build_tw(float2* tw, int t) {
    if (t < 256) {
        float s, c;
        sincosf(-6.283185307179586f * (float)t * (1.0f / 512.0f), &s, &c);
        tw[t] = make_float2(c, s);
    }
}

// Forward radix-2 DIF FFT, 512 pts, 256 thr: natural in, bit-reversed out
// (storage index s holds frequency brev9(s)). Hand-verified at N=4.
__device__ void fft512_dif(float2* d, const float2* tw, int t) {
    #pragma unroll
    for (int m = 256; m >= 1; m >>= 1) {
        __syncthreads();
        int j = t & (m - 1);
        int p = ((t & ~(m - 1)) << 1) | j;
        int q = p + m;
        float2 a = d[p], b = d[q];
        d[p] = make_float2(a.x + b.x, a.y + b.y);
        float2 s = make_float2(a.x - b.x, a.y - b.y);
        d[q] = cmul(s, tw[j * (256 / m)]);
    }
    __syncthreads();
}

// Inverse radix-2 DIT FFT (unnormalized): bit-reversed in, natural out.
__device__ void ifft512_dit(float2* d, const float2* tw, int t) {
    #pragma unroll
    for (int m = 1; m <= 256; m <<= 1) {
        __syncthreads();
        int j = t & (m - 1);
        int p = ((t & ~(m - 1)) << 1) | j;
        int q = p + m;
        float2 w = tw[j * (256 / m)];
        w.y = -w.y;
        float2 b = cmul(d[q], w);
        float2 a = d[p];
        d[p] = make_float2(a.x + b.x, a.y + b.y);
        d[q] = make_float2(a.x - b.x, a.y - b.y);
    }
    __syncthreads();
}

// ---- zero a float range of out ---------------------------------------------
__global__ __launch_bounds__(256)
void zeroF(float* outf, int base) {
    outf[(size_t)base + blockIdx.x * 256 + threadIdx.x] = 0.f;
}

// ===========================================================================
// FAST PATH (needs d_ws >= 58 MB):
//   P planes: 60 half-planes [c][a] of 512x256 fp16 pairs (forward FFT_h out,
//             overwritten in place by the mixed inverse-FFT_w result [c][b]).
//   Krev:     kernels permuted to bit-reversed-w order, fp16 pairs, so the
//             hot-loop K reads are coalesced (vs 4B scattered gathers).
// FFT512 count drops 798,720 -> 184,320 (forward work was 5x redundant over b)
// and dispatches drop 2,642 -> 8.
// ===========================================================================

// R: Krev[p][h][jw] = K[p][h][brev9(jw)], p = b*5+a. grid(25*512).
__global__ __launch_bounds__(256)
void kernelR(const float* __restrict__ kr, const float* __restrict__ ki,
             h2* Krev) {
    int p = blockIdx.x >> 9;       // 0..24
    int h = blockIdx.x & 511;      // natural h
    int t = threadIdx.x;
    __shared__ float2 row[512];
    size_t base = ((size_t)p * G_ + h) * G_;
    row[t]       = make_float2(kr[base + t],       ki[base + t]);
    row[t + 256] = make_float2(kr[base + t + 256], ki[base + t + 256]);
    __syncthreads();
    int j0 = __brev((unsigned)t) >> 23;
    int j1 = __brev((unsigned)(t + 256)) >> 23;
    st2(Krev, base + t,       row[j0]);
    st2(Krev, base + t + 256, row[j1]);
}

// A2: x*mps, pad h, fwd FFT_h, transposed store to P[c*5+a]. grid(12*5*32).
__global__ __launch_bounds__(256)
void kernelA2(const float* __restrict__ xr, const float* __restrict__ xi,
              const float* __restrict__ mr, const float* __restrict__ mi,
              h2* P, int n) {
    int oct = blockIdx.x & 31;
    int a   = (blockIdx.x >> 5) % 5;
    int c   = blockIdx.x / 160;
    int t = threadIdx.x;
    __shared__ float2 tw[256];
    __shared__ float2 rows[8][516];
    build_tw(tw, t);

    int r = t & 7;
    int wc = oct * 8 + r;
    #pragma unroll
    for (int k = 0; k < 8; k++) {
        int h = (t >> 3) + 32 * k;
        size_t xo = (((size_t)n * A_ + a) * H_ + h) * H_ + wc;
        size_t mo = (((size_t)c) * H_ + h) * H_ + wc;
        float xr_ = xr[xo], xi_ = xi[xo];
        float mr_ = mr[mo], mi_ = mi[mo];
        rows[r][h + 128] = make_float2(xr_ * mr_ - xi_ * mi_,
                                       xr_ * mi_ + xi_ * mr_);
        rows[r][(h < 128) ? h : (h + 256)] = make_float2(0.f, 0.f);
    }
    for (int rr = 0; rr < 8; rr++) fft512_dif(&rows[rr][0], tw, t);

    h2* Pp = P + (size_t)(c * 5 + a) * IMGC_;
    #pragma unroll
    for (int k = 0; k < 16; k++) {
        int jh = k * 32 + (t >> 3);
        st2(Pp, (size_t)jh * 256 + oct * 8 + (t & 7), rows[t & 7][jh]);
    }
}

// B2: per (c, jh row): fwd FFT_w of all 5 a-rows ONCE (held in LDS), then for
// each b: G = sum_a Krev[b,a] * F[a] in fp32 regs, inv FFT_w, crop, write back
// in place over P[c*5+b]. grid(12*512).
__global__ __launch_bounds__(256)
void kernelB2(const h2* __restrict__ Krev, h2* P) {
    int jh = blockIdx.x & 511;
    int c  = blockIdx.x >> 9;
    int htrue = __brev((unsigned)jh) >> 23;
    int t = threadIdx.x;
    __shared__ float2 tw[256];
    __shared__ float2 Fa[5][512];
    __shared__ float2 g[512];
    build_tw(tw, t);

    #pragma unroll
    for (int a = 0; a < 5; a++) {
        float2 v = ld2(P, (size_t)(c * 5 + a) * IMGC_ + (size_t)jh * 256 + t);
        Fa[a][t + 128] = v;
        Fa[a][(t < 128) ? t : (t + 256)] = make_float2(0.f, 0.f);
    }
    for (int a = 0; a < 5; a++) fft512_dif(&Fa[a][0], tw, t);

    for (int b = 0; b < 5; b++) {
        __syncthreads();   // all reads of g from previous b are done
        size_t kb = (size_t)b * 1310720 + (size_t)htrue * 512;  // b*5*512*512
        #pragma unroll
        for (int half = 0; half < 2; half++) {
            int jw = t + half * 256;
            float2 acc = make_float2(0.f, 0.f);
            #pragma unroll
            for (int a = 0; a < 5; a++) {
                float2 kv = ld2(Krev, kb + (size_t)a * 262144 + jw);
                float2 fv = Fa[a][jw];
                acc.x += kv.x * fv.x - kv.y * fv.y;
                acc.y += kv.x * fv.y + kv.y * fv.x;
            }
            g[jw] = acc;
        }
        ifft512_dit(g, tw, t);   // leading __syncthreads covers g writes
        float2 res = g[t + 128];
        st2(P, (size_t)(c * 5 + b) * IMGC_ + (size_t)jh * 256 + t, res);
    }
}

// C2: inv FFT_h of P[c*5+b], crop h, Re(conj(mps)*y)*scale, fp32 atomic
// accumulate over c into out. grid(12*5*32).
__global__ __launch_bounds__(256)
void kernelC2(const float* __restrict__ mr, const float* __restrict__ mi,
              const h2* __restrict__ P, float* outf, int n) {
    int oct = blockIdx.x & 31;
    int b   = (blockIdx.x >> 5) % 5;
    int c   = blockIdx.x / 160;
    int t = threadIdx.x;
    __shared__ float2 tw[256];
    __shared__ float2 rows[8][516];
    build_tw(tw, t);

    const h2* Pb = P + (size_t)(c * 5 + b) * IMGC_;
    #pragma unroll
    for (int k = 0; k < 16; k++) {
        int jh = k * 32 + (t >> 3);
        rows[t & 7][jh] = ld2(Pb, (size_t)jh * 256 + oct * 8 + (t & 7));
    }
    __syncthreads();
    for (int rr = 0; rr < 8; rr++) ifft512_dit(&rows[rr][0], tw, t);

    int r = t & 7;
    int wc = oct * 8 + r;
    #pragma unroll
    for (int k = 0; k < 8; k++) {
        int hh = (t >> 3) + 32 * k;
        float2 v = rows[r][hh + 128];
        size_t mo = (((size_t)c) * H_ + hh) * H_ + wc;
        float m_r = mr[mo], m_i = mi[mo];
        float re = (m_r * v.x + m_i * v.y) * SCALE_;
        size_t idx = (((size_t)n * A_ + b) * H_ + hh) * H_ + wc;
        unsafeAtomicAdd(&outf[idx], re);
    }
}

// ===========================================================================
// FALLBACK PATH (proven previous version, used when ws_size < 58 MB)
// ===========================================================================

__global__ __launch_bounds__(256)
void kernelA(const float* __restrict__ xr, const float* __restrict__ xi,
             const float* __restrict__ mr, const float* __restrict__ mi,
             h2* X1, int n, int c, int a) {
    int oct = blockIdx.x;
    int t = threadIdx.x;
    __shared__ float2 tw[256];
    __shared__ float2 rows[8][516];
    build_tw(tw, t);

    int r = t & 7;
    int wc = oct * 8 + r;
    #pragma unroll
    for (int k = 0; k < 8; k++) {
        int h = (t >> 3) + 32 * k;
        size_t xo = (((size_t)n * A_ + a) * H_ + h) * H_ + wc;
        size_t mo = (((size_t)c) * H_ + h) * H_ + wc;
        float xr_ = xr[xo], xi_ = xi[xo];
        float mr_ = mr[mo], mi_ = mi[mo];
        rows[r][h + 128] = make_float2(xr_ * mr_ - xi_ * mi_,
                                       xr_ * mi_ + xi_ * mr_);
        rows[r][(h < 128) ? h : (h + 256)] = make_float2(0.f, 0.f);
    }
    for (int rr = 0; rr < 8; rr++) fft512_dif(&rows[rr][0], tw, t);

    #pragma unroll
    for (int k = 0; k < 16; k++) {
        int jh = k * 32 + (t >> 3);
        st2(X1, (size_t)jh * 256 + oct * 8 + (t & 7), rows[t & 7][jh]);
    }
}

__global__ __launch_bounds__(256)
void kernelB(const float* __restrict__ kr, const float* __restrict__ ki,
             const h2* X1, h2* X2, int b, int a) {
    int jh = blockIdx.x;
    int htrue = __brev((unsigned)jh) >> 23;
    int t = threadIdx.x;
    __shared__ float2 tw[256];
    __shared__ float2 F[512];
    __shared__ float2 g[512];
    build_tw(tw, t);

    float2 v = ld2(X1, (size_t)jh * 256 + t);
    F[t + 128] = v;
    F[(t < 128) ? t : (t + 256)] = make_float2(0.f, 0.f);
    fft512_dif(F, tw, t);

    #pragma unroll
    for (int half = 0; half < 2; half++) {
        int jw = t + half * 256;
        int wtrue = __brev((unsigned)jw) >> 23;
        size_t kidx = (((size_t)(b * A_ + a)) * G_ + htrue) * G_ + wtrue;
        g[jw] = cmul(make_float2(kr[kidx], ki[kidx]), F[jw]);
    }
    ifft512_dit(g, tw, t);

    float2 res = g[t + 128];
    size_t o = (size_t)jh * 256 + t;
    if (a == 0) st2(X2, o, res);
    else {
        float2 cur = ld2(X2, o);
        st2(X2, o, make_float2(cur.x + res.x, cur.y + res.y));
    }
}

__global__ __launch_bounds__(256)
void kernelC(const float* __restrict__ mr, const float* __restrict__ mi,
             const h2* X2, float* outf, int n, int c, int b) {
    int oct = blockIdx.x;
    int t = threadIdx.x;
    __shared__ float2 tw[256];
    __shared__ float2 rows[8][516];
    build_tw(tw, t);

    #pragma unroll
    for (int k = 0; k < 16; k++) {
        int jh = k * 32 + (t >> 3);
        rows[t & 7][jh] = ld2(X2, (size_t)jh * 256 + oct * 8 + (t & 7));
    }
    __syncthreads();
    for (int rr = 0; rr < 8; rr++) ifft512_dit(&rows[rr][0], tw, t);

    int r = t & 7;
    int wc = oct * 8 + r;
    #pragma unroll
    for (int k = 0; k < 8; k++) {
        int hh = (t >> 3) + 32 * k;
        float2 v = rows[r][hh + 128];
        size_t mo = (((size_t)c) * H_ + hh) * H_ + wc;
        float m_r = mr[mo], m_i = mi[mo];
        float re = (m_r * v.x + m_i * v.y) * SCALE_;
        size_t idx = (((size_t)n * A_ + b) * H_ + hh) * H_ + wc;
        outf[idx] += re;
    }
}

// ===========================================================================
extern "C" void kernel_launch(void* const* d_in, const int* in_sizes, int n_in,
                              void* d_out, int out_size, void* d_ws, size_t ws_size,
                              hipStream_t stream) {
    const float* xr = (const float*)d_in[0];
    const float* xi = (const float*)d_in[1];
    const float* mr = (const float*)d_in[2];
    const float* mi = (const float*)d_in[3];
    const float* kr = (const float*)d_in[4];
    const float* ki = (const float*)d_in[5];
    float* outf = (float*)d_out;
    (void)in_sizes; (void)n_in; (void)out_size;

    const size_t PLANES_BYTES = 60ull * IMGC_ * sizeof(h2);   // 31,457,280
    const size_t KREV_BYTES   = 25ull * G_ * G_ * sizeof(h2); // 26,214,400

    if (d_ws != nullptr && ws_size >= PLANES_BYTES + KREV_BYTES) {
        // ---- fast path: dedup'd forward FFTs, coalesced fp16 Krev, 8 dispatches
        h2* P    = (h2*)d_ws;
        h2* Krev = (h2*)((char*)d_ws + PLANES_BYTES);
        zeroF<<<OUTF_ / 256, 256, 0, stream>>>(outf, 0);
        kernelR<<<25 * 512, 256, 0, stream>>>(kr, ki, Krev);
        for (int n = 0; n < N_; n++) {
            kernelA2<<<C_ * A_ * 32, 256, 0, stream>>>(xr, xi, mr, mi, P, n);
            kernelB2<<<C_ * 512, 256, 0, stream>>>(Krev, P);
            kernelC2<<<C_ * A_ * 32, 256, 0, stream>>>(mr, mi, P, outf, n);
        }
        return;
    }

    // ---- fallback: previous proven version (out + consumed-input scratch) ----
    zeroF<<<HALFF_ / 256, 256, 0, stream>>>(outf, 0);
    {
        h2* X1 = (h2*)(outf + HALFF_);
        h2* X2 = (h2*)(outf + HALFF_ + IMGC_);
        for (int c = 0; c < C_; c++)
            for (int b = 0; b < A_; b++) {
                for (int a = 0; a < A_; a++) {
                    kernelA<<<32, 256, 0, stream>>>(xr, xi, mr, mi, X1, 0, c, a);
                    kernelB<<<512, 256, 0, stream>>>(kr, ki, X1, X2, b, a);
                }
                kernelC<<<32, 256, 0, stream>>>(mr, mi, X2, outf, 0, c, b);
            }
    }

    zeroF<<<HALFF_ / 256, 256, 0, stream>>>(outf, HALFF_);
    {
        h2* X1 = (h2*)d_in[0];
        h2* X2 = (h2*)d_in[1];
        for (int c = 0; c < C_; c++)
            for (int b = 0; b < A_; b++) {
                for (int a = 0; a < A_; a++) {
                    kernelA<<<32, 256, 0, stream>>>(xr, xi, mr, mi, X1, 1, c, a);
                    kernelB<<<512, 256, 0, stream>>>(kr, ki, X1, X2, b, a);
                }
                kernelC<<<32, 256, 0, stream>>>(mr, mi, X2, outf, 1, c, b);
            }
    }
}

// Round 3
// 512.931 us; speedup vs baseline: 24.1573x; 1.1168x over previous
//
#include <hip/hip_runtime.h>
#include <math.h>

#define N_ 2
#define A_ 5
#define C_ 12
#define H_ 256
#define G_ 512
// out = 4 * ifft_ortho(K * fft_ortho(...)) ==> 4/(512*512) on unnormalized FFTs
#define SCALE_ (4.0f / 262144.0f)
#define OUTF_ 655360       // out = fp32 REAL part, [2,5,256,256]
#define HALFF_ 327680      // per-n float count
#define IMGC_ 131072       // 512*256 complex: one spectral half-plane (h2 elems)

// ---- fp16-pair scratch ------------------------------------------------------
struct __attribute__((aligned(4))) h2 { _Float16 x, y; };
struct __attribute__((aligned(8))) h2x2 { _Float16 x0, y0, x1, y1; };
__device__ __forceinline__ float2 ld2(const h2* p, size_t i) {
    h2 v = p[i]; return make_float2((float)v.x, (float)v.y);
}
__device__ __forceinline__ void st2(h2* p, size_t i, float2 v) {
    float x = fminf(fmaxf(v.x, -60000.f), 60000.f);   // never store inf
    float y = fminf(fmaxf(v.y, -60000.f), 60000.f);
    h2 o; o.x = (_Float16)x; o.y = (_Float16)y; p[i] = o;
}

__device__ __forceinline__ float2 cmul(float2 a, float2 b) {
    return make_float2(a.x * b.x - a.y * b.y, a.x * b.y + a.y * b.x);
}

// Per-stage twiddle tables, 511 float2 entries total:
//   stage with half-size m (fwd DIF order m=256..1) occupies twS[off..off+m),
//   off = 0,256,384,448,480,496,504,508,510.  Entry j = w^(j*(256/m)),
//   w = exp(-2*pi*i/512).  Stride-1 per stage -> bank-conflict-free reads.
__device__ __forceinline__ void build_twS(float2* twS, int t) {
    float s, c;
    sincosf(-6.283185307179586f * (float)t * (1.0f / 512.0f), &s, &c);
    twS[t] = make_float2(c, s);
    __syncthreads();
    int off = 256;
    #pragma unroll
    for (int sh = 1; sh <= 8; sh++) {
        int sz = 256 >> sh;
        if (t < sz) twS[off + t] = twS[t << sh];
        off += sz;
    }
    // no trailing sync: first barrier inside the FFT covers these writes
    // (copies write [256,511), first FFT stage reads only [0,256)).
}

// Forward radix-2 DIF FFT, 512 pts, 256 thr: natural in, bit-reversed out.
// Barriers only while butterflies cross 128-elem wave chunks (m>=64);
// for m<=32 each wave's p,q stay inside [128*wave, 128*wave+128) -> wave-sync.
__device__ void fft512_dif(float2* d, const float2* twS, int t) {
    int off = 0;
    #pragma unroll
    for (int m = 256; m >= 1; m >>= 1) {
        if (m >= 64) __syncthreads();
        else __builtin_amdgcn_wave_barrier();
        int j = t & (m - 1);
        int p = ((t & ~(m - 1)) << 1) | j;
        int q = p + m;
        float2 a = d[p], b = d[q];
        d[p] = make_float2(a.x + b.x, a.y + b.y);
        float2 s = make_float2(a.x - b.x, a.y - b.y);
        d[q] = cmul(s, twS[off + j]);
        off += m;
    }
    __syncthreads();
}

// Inverse radix-2 DIT FFT (unnormalized): bit-reversed in, natural out.
// Initial barrier (m==1) covers caller's writes to d; m<=64 stages wave-local.
__device__ void ifft512_dit(float2* d, const float2* twS, int t) {
    int off = 510;
    #pragma unroll
    for (int m = 1; m <= 256; m <<= 1) {
        if (m == 1 || m >= 128) __syncthreads();
        else __builtin_amdgcn_wave_barrier();
        int j = t & (m - 1);
        int p = ((t & ~(m - 1)) << 1) | j;
        int q = p + m;
        float2 w = twS[off + j];
        w.y = -w.y;
        float2 b = cmul(d[q], w);
        float2 a = d[p];
        d[p] = make_float2(a.x + b.x, a.y + b.y);
        d[q] = make_float2(a.x - b.x, a.y - b.y);
        off -= (m << 1);
    }
    __syncthreads();
}

// ---- zero a float range of out ---------------------------------------------
__global__ __launch_bounds__(256)
void zeroF(float* outf, int base) {
    outf[(size_t)base + blockIdx.x * 256 + threadIdx.x] = 0.f;
}

// ===========================================================================
// FAST PATH (needs d_ws >= 58 MB)
// ===========================================================================

// R: Krev[p][h][jw] = K[p][h][brev9(jw)], p = b*5+a. grid(25*512).
__global__ __launch_bounds__(256)
void kernelR(const float* __restrict__ kr, const float* __restrict__ ki,
             h2* Krev) {
    int p = blockIdx.x >> 9;       // 0..24
    int h = blockIdx.x & 511;      // natural h
    int t = threadIdx.x;
    __shared__ float2 row[512];
    size_t base = ((size_t)p * G_ + h) * G_;
    row[t]       = make_float2(kr[base + t],       ki[base + t]);
    row[t + 256] = make_float2(kr[base + t + 256], ki[base + t + 256]);
    __syncthreads();
    int j0 = __brev((unsigned)t) >> 23;
    int j1 = __brev((unsigned)(t + 256)) >> 23;
    st2(Krev, base + t,       row[j0]);
    st2(Krev, base + t + 256, row[j1]);
}

// A2: x*mps, pad h, fwd FFT_h, transposed store to P[c*5+a]. grid(12*5*32).
__global__ __launch_bounds__(256)
void kernelA2(const float* __restrict__ xr, const float* __restrict__ xi,
              const float* __restrict__ mr, const float* __restrict__ mi,
              h2* P, int n) {
    int oct = blockIdx.x & 31;
    int a   = (blockIdx.x >> 5) % 5;
    int c   = blockIdx.x / 160;
    int t = threadIdx.x;
    __shared__ float2 twS[511];
    __shared__ float2 rows[8][516];
    build_twS(twS, t);

    int r = t & 7;
    int wc = oct * 8 + r;
    #pragma unroll
    for (int k = 0; k < 8; k++) {
        int h = (t >> 3) + 32 * k;
        size_t xo = (((size_t)n * A_ + a) * H_ + h) * H_ + wc;
        size_t mo = (((size_t)c) * H_ + h) * H_ + wc;
        float xr_ = xr[xo], xi_ = xi[xo];
        float mr_ = mr[mo], mi_ = mi[mo];
        rows[r][h + 128] = make_float2(xr_ * mr_ - xi_ * mi_,
                                       xr_ * mi_ + xi_ * mr_);
        rows[r][(h < 128) ? h : (h + 256)] = make_float2(0.f, 0.f);
    }
    for (int rr = 0; rr < 8; rr++) fft512_dif(&rows[rr][0], twS, t);

    h2* Pp = P + (size_t)(c * 5 + a) * IMGC_;
    #pragma unroll
    for (int k = 0; k < 16; k++) {
        int jh = k * 32 + (t >> 3);
        st2(Pp, (size_t)jh * 256 + oct * 8 + (t & 7), rows[t & 7][jh]);
    }
}

// B2: per (c, jh row): fwd FFT_w of all 5 a-rows ONCE (held in LDS), then for
// each b: G = sum_a Krev[b,a]*F[a] in fp32 regs, inv FFT_w, crop, write back
// in place over P[c*5+b]. grid(12*512), jh-major so same-jh blocks (which read
// the identical Krev slice) are adjacent in dispatch order.
__global__ __launch_bounds__(256)
void kernelB2(const h2* __restrict__ Krev, h2* P) {
    int c  = blockIdx.x % 12;
    int jh = blockIdx.x / 12;
    int htrue = __brev((unsigned)jh) >> 23;
    int t = threadIdx.x;
    __shared__ float2 twS[511];
    __shared__ float2 Fa[5][512];
    __shared__ float2 g[512];
    build_twS(twS, t);

    #pragma unroll
    for (int a = 0; a < 5; a++) {
        float2 v = ld2(P, (size_t)(c * 5 + a) * IMGC_ + (size_t)jh * 256 + t);
        Fa[a][t + 128] = v;
        Fa[a][(t < 128) ? t : (t + 256)] = make_float2(0.f, 0.f);
    }
    for (int a = 0; a < 5; a++) fft512_dif(&Fa[a][0], twS, t);

    int jw = 2 * t;
    for (int b = 0; b < 5; b++) {
        __syncthreads();   // all reads of g from previous b are done
        size_t kb = (size_t)b * 1310720 + (size_t)htrue * 512;  // b*5*512*512
        float2 acc0 = make_float2(0.f, 0.f);
        float2 acc1 = make_float2(0.f, 0.f);
        #pragma unroll
        for (int a = 0; a < 5; a++) {
            const h2x2* Kp =
                reinterpret_cast<const h2x2*>(Krev + kb + (size_t)a * 262144);
            h2x2 kv = Kp[t];   // jw, jw+1 in one 8B load
            float2 f0 = Fa[a][jw], f1 = Fa[a][jw + 1];
            float k0x = (float)kv.x0, k0y = (float)kv.y0;
            float k1x = (float)kv.x1, k1y = (float)kv.y1;
            acc0.x += k0x * f0.x - k0y * f0.y;
            acc0.y += k0x * f0.y + k0y * f0.x;
            acc1.x += k1x * f1.x - k1y * f1.y;
            acc1.y += k1x * f1.y + k1y * f1.x;
        }
        g[jw] = acc0;
        g[jw + 1] = acc1;
        ifft512_dit(g, twS, t);   // leading barrier covers g writes
        float2 res = g[t + 128];
        st2(P, (size_t)(c * 5 + b) * IMGC_ + (size_t)jh * 256 + t, res);
    }
}

// C2: inv FFT_h of P[c*5+b], crop h, Re(conj(mps)*y)*scale, fp32 atomic
// accumulate over c into out. grid(12*5*32).
__global__ __launch_bounds__(256)
void kernelC2(const float* __restrict__ mr, const float* __restrict__ mi,
              const h2* __restrict__ P, float* outf, int n) {
    int oct = blockIdx.x & 31;
    int b   = (blockIdx.x >> 5) % 5;
    int c   = blockIdx.x / 160;
    int t = threadIdx.x;
    __shared__ float2 twS[511];
    __shared__ float2 rows[8][516];
    build_twS(twS, t);

    const h2* Pb = P + (size_t)(c * 5 + b) * IMGC_;
    #pragma unroll
    for (int k = 0; k < 16; k++) {
        int jh = k * 32 + (t >> 3);
        rows[t & 7][jh] = ld2(Pb, (size_t)jh * 256 + oct * 8 + (t & 7));
    }
    for (int rr = 0; rr < 8; rr++) ifft512_dit(&rows[rr][0], twS, t);

    int r = t & 7;
    int wc = oct * 8 + r;
    #pragma unroll
    for (int k = 0; k < 8; k++) {
        int hh = (t >> 3) + 32 * k;
        float2 v = rows[r][hh + 128];
        size_t mo = (((size_t)c) * H_ + hh) * H_ + wc;
        float m_r = mr[mo], m_i = mi[mo];
        float re = (m_r * v.x + m_i * v.y) * SCALE_;
        size_t idx = (((size_t)n * A_ + b) * H_ + hh) * H_ + wc;
        unsafeAtomicAdd(&outf[idx], re);
    }
}

// ===========================================================================
// FALLBACK PATH (used when ws_size < 58 MB)
// ===========================================================================

__global__ __launch_bounds__(256)
void kernelA(const float* __restrict__ xr, const float* __restrict__ xi,
             const float* __restrict__ mr, const float* __restrict__ mi,
             h2* X1, int n, int c, int a) {
    int oct = blockIdx.x;
    int t = threadIdx.x;
    __shared__ float2 twS[511];
    __shared__ float2 rows[8][516];
    build_twS(twS, t);

    int r = t & 7;
    int wc = oct * 8 + r;
    #pragma unroll
    for (int k = 0; k < 8; k++) {
        int h = (t >> 3) + 32 * k;
        size_t xo = (((size_t)n * A_ + a) * H_ + h) * H_ + wc;
        size_t mo = (((size_t)c) * H_ + h) * H_ + wc;
        float xr_ = xr[xo], xi_ = xi[xo];
        float mr_ = mr[mo], mi_ = mi[mo];
        rows[r][h + 128] = make_float2(xr_ * mr_ - xi_ * mi_,
                                       xr_ * mi_ + xi_ * mr_);
        rows[r][(h < 128) ? h : (h + 256)] = make_float2(0.f, 0.f);
    }
    for (int rr = 0; rr < 8; rr++) fft512_dif(&rows[rr][0], twS, t);

    #pragma unroll
    for (int k = 0; k < 16; k++) {
        int jh = k * 32 + (t >> 3);
        st2(X1, (size_t)jh * 256 + oct * 8 + (t & 7), rows[t & 7][jh]);
    }
}

__global__ __launch_bounds__(256)
void kernelB(const float* __restrict__ kr, const float* __restrict__ ki,
             const h2* X1, h2* X2, int b, int a) {
    int jh = blockIdx.x;
    int htrue = __brev((unsigned)jh) >> 23;
    int t = threadIdx.x;
    __shared__ float2 twS[511];
    __shared__ float2 F[512];
    __shared__ float2 g[512];
    build_twS(twS, t);

    float2 v = ld2(X1, (size_t)jh * 256 + t);
    F[t + 128] = v;
    F[(t < 128) ? t : (t + 256)] = make_float2(0.f, 0.f);
    fft512_dif(F, twS, t);

    #pragma unroll
    for (int half = 0; half < 2; half++) {
        int jw = t + half * 256;
        int wtrue = __brev((unsigned)jw) >> 23;
        size_t kidx = (((size_t)(b * A_ + a)) * G_ + htrue) * G_ + wtrue;
        g[jw] = cmul(make_float2(kr[kidx], ki[kidx]), F[jw]);
    }
    ifft512_dit(g, twS, t);

    float2 res = g[t + 128];
    size_t o = (size_t)jh * 256 + t;
    if (a == 0) st2(X2, o, res);
    else {
        float2 cur = ld2(X2, o);
        st2(X2, o, make_float2(cur.x + res.x, cur.y + res.y));
    }
}

__global__ __launch_bounds__(256)
void kernelC(const float* __restrict__ mr, const float* __restrict__ mi,
             const h2* X2, float* outf, int n, int c, int b) {
    int oct = blockIdx.x;
    int t = threadIdx.x;
    __shared__ float2 twS[511];
    __shared__ float2 rows[8][516];
    build_twS(twS, t);

    #pragma unroll
    for (int k = 0; k < 16; k++) {
        int jh = k * 32 + (t >> 3);
        rows[t & 7][jh] = ld2(X2, (size_t)jh * 256 + oct * 8 + (t & 7));
    }
    for (int rr = 0; rr < 8; rr++) ifft512_dit(&rows[rr][0], twS, t);

    int r = t & 7;
    int wc = oct * 8 + r;
    #pragma unroll
    for (int k = 0; k < 8; k++) {
        int hh = (t >> 3) + 32 * k;
        float2 v = rows[r][hh + 128];
        size_t mo = (((size_t)c) * H_ + hh) * H_ + wc;
        float m_r = mr[mo], m_i = mi[mo];
        float re = (m_r * v.x + m_i * v.y) * SCALE_;
        size_t idx = (((size_t)n * A_ + b) * H_ + hh) * H_ + wc;
        outf[idx] += re;
    }
}

// ===========================================================================
extern "C" void kernel_launch(void* const* d_in, const int* in_sizes, int n_in,
                              void* d_out, int out_size, void* d_ws, size_t ws_size,
                              hipStream_t stream) {
    const float* xr = (const float*)d_in[0];
    const float* xi = (const float*)d_in[1];
    const float* mr = (const float*)d_in[2];
    const float* mi = (const float*)d_in[3];
    const float* kr = (const float*)d_in[4];
    const float* ki = (const float*)d_in[5];
    float* outf = (float*)d_out;
    (void)in_sizes; (void)n_in; (void)out_size;

    const size_t PLANES_BYTES = 60ull * IMGC_ * sizeof(h2);   // 31,457,280
    const size_t KREV_BYTES   = 25ull * G_ * G_ * sizeof(h2); // 26,214,400

    if (d_ws != nullptr && ws_size >= PLANES_BYTES + KREV_BYTES) {
        h2* P    = (h2*)d_ws;
        h2* Krev = (h2*)((char*)d_ws + PLANES_BYTES);
        zeroF<<<OUTF_ / 256, 256, 0, stream>>>(outf, 0);
        kernelR<<<25 * 512, 256, 0, stream>>>(kr, ki, Krev);
        for (int n = 0; n < N_; n++) {
            kernelA2<<<C_ * A_ * 32, 256, 0, stream>>>(xr, xi, mr, mi, P, n);
            kernelB2<<<C_ * 512, 256, 0, stream>>>(Krev, P);
            kernelC2<<<C_ * A_ * 32, 256, 0, stream>>>(mr, mi, P, outf, n);
        }
        return;
    }

    // ---- fallback ----
    zeroF<<<HALFF_ / 256, 256, 0, stream>>>(outf, 0);
    {
        h2* X1 = (h2*)(outf + HALFF_);
        h2* X2 = (h2*)(outf + HALFF_ + IMGC_);
        for (int c = 0; c < C_; c++)
            for (int b = 0; b < A_; b++) {
                for (int a = 0; a < A_; a++) {
                    kernelA<<<32, 256, 0, stream>>>(xr, xi, mr, mi, X1, 0, c, a);
                    kernelB<<<512, 256, 0, stream>>>(kr, ki, X1, X2, b, a);
                }
                kernelC<<<32, 256, 0, stream>>>(mr, mi, X2, outf, 0, c, b);
            }
    }

    zeroF<<<HALFF_ / 256, 256, 0, stream>>>(outf, HALFF_);
    {
        h2* X1 = (h2*)d_in[0];
        h2* X2 = (h2*)d_in[1];
        for (int c = 0; c < C_; c++)
            for (int b = 0; b < A_; b++) {
                for (int a = 0; a < A_; a++) {
                    kernelA<<<32, 256, 0, stream>>>(xr, xi, mr, mi, X1, 1, c, a);
                    kernelB<<<512, 256, 0, stream>>>(kr, ki, X1, X2, b, a);
                }
                kernelC<<<32, 256, 0, stream>>>(mr, mi, X2, outf, 1, c, b);
            }
    }
}